// Round 7
// baseline (82.383 us; speedup 1.0000x reference)
//
#include <hip/hip_runtime.h>
#include <hip/hip_bf16.h>

// Grouped int32 GEMM, scaled, f32 out.
// A flat: per group [k, M] (k-major). B flat: per group [k, N].
// O[g][m][n] = (sum_k A[k][m]*B[k][n]) * scale[g][n] * pts[g][m]
// Values 0..127 -> exact in bf16; sums < 2^24 -> exact in f32 MFMA accum.
//
// Round 7 = verified numerics (r2..r6) + WIDE TILES (128m x 512n).
// Theory: all prior rounds wrote output rows as 512B pieces at 8KB stride
// -> ~1 DRAM page-activate per 512B -> effective write BW ~4 TB/s vs the
// fill kernel's 7 TB/s (long contiguous runs). 512-wide tiles make each
// row visit a 2KB contiguous run (4 waves x adjacent 512B quarters,
// sequential stores per wave) -> expect ~5.5-6.5 TB/s write pacing.
// Cost: 92KB LDS -> 1 block/CU (r3 showed 1 block/CU is neutral).

#define M_ 2048
#define N_ 2048
#define G_ 16
#define BM 128
#define BN 512
#define KP 72   // LDS row stride in bf16 elems (144B, multiple of 16B for b128)
#define KT 64   // K tile (>= max group k)

typedef __attribute__((ext_vector_type(8))) short bf16x8;
typedef __attribute__((ext_vector_type(4))) float f32x4;
typedef __attribute__((ext_vector_type(4))) int   int4v;

// 8B-granule XOR swizzle within a row: spreads staging writes across banks.
// Applied identically on write and read (same involution both sides).
__device__ __forceinline__ int swz8(int row, int g) {
    return g ^ (((row >> 2) & 3) << 2);
}

// Stage one KT x NCOLS tile (src [k, ld], cols col0..col0+NCOLS-1) into
// dst[col][k] bf16 with granule swizzle, zero-padded to KT in k.
// Each cell = 4 cols x 4 k: 4 int4 loads -> register 4x4 transpose ->
// 4 swizzled 8B LDS writes. Lane-consecutive cells -> 1KB/wave coalesced.
template <int NCOLS>
__device__ __forceinline__ void stage_tile_v(const int* __restrict__ srcg, int ld,
                                             int col0, int kg,
                                             unsigned short (*dst)[KP], int tid)
{
    constexpr int C4    = NCOLS / 4;          // cells per k-slice
    constexpr int NITER = (C4 * 16) / 256;    // total cells / threads
    #pragma unroll
    for (int cc = 0; cc < NITER; ++cc) {
        const int c  = tid + cc * 256;
        const int mc = c & (C4 - 1);          // col-cell
        const int kc = c / C4;                // k-granule 0..15
        const int k0 = kc * 4;
        const int mm = mc * 4;

        if (k0 >= kg) {
            uint2 z = {0u, 0u};
            #pragma unroll
            for (int j = 0; j < 4; ++j) {
                int r = mm + j;
                *(uint2*)((char*)&dst[r][0] + swz8(r, kc) * 8) = z;
            }
        } else {
            int4v L[4];
            const int off = k0 * ld + col0 + mm;    // 32-bit element offset
            #pragma unroll
            for (int i = 0; i < 4; ++i) {
                L[i] = (k0 + i < kg) ? *(const int4v*)(srcg + off + i * ld)
                                     : (int4v){0, 0, 0, 0};
            }
            #pragma unroll
            for (int j = 0; j < 4; ++j) {
                // bf16 of L[0..3][j]: exact for 0..127
                unsigned u0 = __float_as_uint((float)L[0][j]);
                unsigned u1 = __float_as_uint((float)L[1][j]);
                unsigned u2 = __float_as_uint((float)L[2][j]);
                unsigned u3 = __float_as_uint((float)L[3][j]);
                uint2 w;
                w.x = (u0 >> 16) | (u1 & 0xFFFF0000u);
                w.y = (u2 >> 16) | (u3 & 0xFFFF0000u);
                int r = mm + j;
                *(uint2*)((char*)&dst[r][0] + swz8(r, kc) * 8) = w;
            }
        }
    }
}

__device__ __forceinline__ bf16x8 frag_read(const unsigned short (*s)[KP],
                                            int r, int gg)
{
    return *(const bf16x8*)((const char*)&s[r][0] + swz8(r, gg) * 8);
}

__global__ __launch_bounds__(256, 1)
void grouped_gemm_kernel(const int* __restrict__ a,
                         const int* __restrict__ b,
                         const float* __restrict__ scale,
                         const float* __restrict__ pts,
                         const int* __restrict__ gl,
                         float* __restrict__ out)
{
    __shared__ __align__(16) unsigned short As[BM][KP];   // 18 KB
    __shared__ __align__(16) unsigned short Bs[BN][KP];   // 72 KB

    const int tid = threadIdx.x;
    // XCD-chunked swizzle (bijective: 1024 = 8*128): each XCD gets 128
    // consecutive virtual tiles = 2 whole groups -> inputs L2-resident.
    const int bx0 = blockIdx.x;
    const int bx  = (bx0 & 7) * 128 + (bx0 >> 3);
    const int ind = bx >> 6;        // 64 tiles per group (16 m x 4 n)
    const int t   = bx & 63;
    const int m0  = (t >> 2) * BM;
    const int n0  = (t & 3) * BN;   // n fastest: consecutive tiles share A-strip

    const int prefix = (ind == 0) ? 0 : gl[ind - 1];
    const int kg     = gl[ind] - prefix;

    float* outg = out + (size_t)ind * M_ * N_;

    if (kg <= 0) {
        // empty group: zero-fill, row-major forward, 1KB/wave-instr
        f32x4 z = {0.f, 0.f, 0.f, 0.f};
        #pragma unroll 4
        for (int i = 0; i < (BM * BN / 4) / 256; ++i) {
            int idx = i * 256 + tid;
            int r   = idx >> 7;             // BN/4 = 128 f32x4 per row
            int c   = (idx & 127) * 4;
            *(f32x4*)(outg + (size_t)(m0 + r) * N_ + n0 + c) = z;
        }
        return;
    }

    const int* ag = a + (size_t)prefix * M_;
    const int* bg = b + (size_t)prefix * N_;

    const int wid  = tid >> 6;      // 4 waves: wave w owns n-quarter w*128
    const int lane = tid & 63;
    const int l16  = lane & 15;
    const int lq   = lane >> 4;
    const int wn   = wid * 128;

    // single LDS fill: KT=64 covers every group's k (kg <= 64, zero-padded)
    stage_tile_v<BM>(ag, M_, m0, kg, As, tid);
    stage_tile_v<BN>(bg, N_, n0, kg, Bs, tid);
    __syncthreads();

    // B fragments + scales for this wave's 128-col slice (persistent)
    bf16x8 bfr0[8], bfr1[8];
    #pragma unroll
    for (int f = 0; f < 8; ++f) {
        bfr0[f] = frag_read(Bs, wn + f * 16 + l16, 0 + lq * 2);
        bfr1[f] = frag_read(Bs, wn + f * 16 + l16, 8 + lq * 2);
    }

    const float* scg = scale + (size_t)ind * N_;
    const float* ptg = pts + (size_t)ind * M_;

    f32x4 sc[8];
    #pragma unroll
    for (int f = 0; f < 8; ++f)
        sc[f] = *(const f32x4*)&scg[n0 + wn + f * 16 + lq * 4];

    // m-outer / n-inner: each row is written as 8 sequential 64B stores
    // (512B forward run per wave; 4 waves cover adjacent quarters -> 2KB
    // contiguous per output-row visit). Both K=32 MFMA steps always run
    // (upper half staged as zeros when kg <= 32 -> exact).
    #pragma unroll 1
    for (int mf = 0; mf < 8; ++mf) {
        const int mloc = mf * 16 + l16;
        bf16x8 afr0 = frag_read(As, mloc, 0 + lq * 2);
        bf16x8 afr1 = frag_read(As, mloc, 8 + lq * 2);
        const float pt = ptg[m0 + mloc];
        float* orow = outg + (size_t)(m0 + mloc) * N_ + n0 + wn + lq * 4;
        #pragma unroll
        for (int f = 0; f < 8; ++f) {
            // swapped operands: D = B_frag x A_frag -> lane holds
            // m = l16, n = lq*4 + r -> f32x4 store along n
            f32x4 d = __builtin_amdgcn_mfma_f32_16x16x32_bf16(
                bfr0[f], afr0, (f32x4){0.f, 0.f, 0.f, 0.f}, 0, 0, 0);
            d = __builtin_amdgcn_mfma_f32_16x16x32_bf16(
                bfr1[f], afr1, d, 0, 0, 0);
            f32x4 v;
            #pragma unroll
            for (int r = 0; r < 4; ++r)
                v[r] = (d[r] * sc[f][r]) * pt;   // same mul order as reference
            *(f32x4*)(orow + f * 16) = v;
        }
    }
}

extern "C" void kernel_launch(void* const* d_in, const int* in_sizes, int n_in,
                              void* d_out, int out_size, void* d_ws, size_t ws_size,
                              hipStream_t stream) {
    const int*   a     = (const int*)d_in[0];
    const int*   b     = (const int*)d_in[1];
    const float* scale = (const float*)d_in[2];
    const float* pts   = (const float*)d_in[3];
    const int*   gl    = (const int*)d_in[4];
    float*       out   = (float*)d_out;

    dim3 grid(G_ * (M_ / BM) * (N_ / BN));   // 16 * 16 * 4 = 1024
    dim3 block(256);
    grouped_gemm_kernel<<<grid, block, 0, stream>>>(a, b, scale, pts, gl, out);
}